// Round 9
// baseline (120.468 us; speedup 1.0000x reference)
//
#include <hip/hip_runtime.h>
#include <stdint.h>

#define HH 512
#define WW 512
#define NB 8
#define RAD 10
#define NPASS 51
#define WPR 16                 // u32 words per row
#define IMG_WORDS (HH*WPR)     // 8192 words per image
#define STRIDE 540             // words per LDS column: 12 low guard + 512 + 16 high guard
#define GLO 12                 // low guard rows (keeps b128 writes 16B-aligned)
#define RPT 16                 // rows per thread

// ---- Kernel 1: det bits (x1>x0) + per-BLOCK argmax key (no atomics) --------
__global__ __launch_bounds__(256) void k_det(const float* __restrict__ in,
                                             uint32_t* __restrict__ det,
                                             unsigned long long* __restrict__ keys) {
    __shared__ unsigned long long red[4];
    int tid  = blockIdx.x * 256 + threadIdx.x;
    int lane = threadIdx.x & 63;
    int wv   = threadIdx.x >> 6;
    int wave = tid >> 6;
    long long base = (long long)wave * 256;     // 4 rounds x 64 pixels
    unsigned long long best = 0;
    const float2* in2 = (const float2*)in;
    #pragma unroll
    for (int j = 0; j < 4; ++j) {
        long long p = base + j * 64 + lane;
        float2 v = in2[p];
        // round(softmax_1(v)) == 1  <=>  v.y > v.x   (exact; no expf needed)
        float d = v.y - v.x;
        int pred = (d > 0.0f);
        unsigned long long bits = __ballot(pred);
        if (lane == 0) ((unsigned long long*)det)[wave * 4 + j] = bits;
        // argmax of softmax_1 == argmax of d (sigmoid strictly monotone).
        uint32_t du = __float_as_uint(d);
        uint32_t mono = (du & 0x80000000u) ? ~du : (du | 0x80000000u);
        uint32_t pix = (uint32_t)(p & (HH * WW - 1));
        unsigned long long key = ((unsigned long long)mono << 32)
                               | (unsigned long long)(0xFFFFFFFFu - pix);
        best = key > best ? key : best;
    }
    #pragma unroll
    for (int s = 32; s > 0; s >>= 1) {
        unsigned long long o = __shfl_xor(best, s);
        best = o > best ? o : best;
    }
    if (lane == 0) red[wv] = best;
    __syncthreads();
    if (threadIdx.x == 0) {
        unsigned long long b0 = red[0], b1 = red[1], b2 = red[2], b3 = red[3];
        b0 = b0 > b1 ? b0 : b1;
        b2 = b2 > b3 ? b2 : b3;
        keys[blockIdx.x] = b0 > b2 ? b0 : b2;   // plain store, no atomics
    }
}

// ---- Kernel 2: geodesic dilation, barrier-free neighbor-epoch sync ---------
// Wave g owns rows 64g..64g+63. V needs H rows +/-10 -> only waves g-1,g+1.
// Protocol per iter: write H to hb[it&1]; release ep[g]=it+1; acquire-spin
// ep[g+/-1] >= it+1; read halo; compute V. Safety: wave g+1 reaches its
// H(it+2) write (same parity buffer) only after its V(it+1), which spins on
// ep[g] >= it+2, published only after g's V(it) reads finished. Fixed 51
// iterations (no early exit): extra passes at a fixed point are idempotent.
__global__ __launch_bounds__(512) void k_grow(const uint32_t* __restrict__ det,
                                              const unsigned long long* __restrict__ keys,
                                              uint32_t* __restrict__ outmask) {
    __shared__ __align__(16) uint32_t hb[2][WPR * STRIDE];  // 69 KB, col-major
    __shared__ uint32_t ep[8];              // per-wave published H-epoch
    __shared__ unsigned long long redk[4];
    int b    = blockIdx.x;
    int t    = threadIdx.x;
    int lane = t & 63;
    int wvid = t >> 6;                   // wave 0..7 (owns rows 64*wvid..+63)
    int w    = t & 15;                   // word-in-row == lane&15 (DPP row!)
    int r0   = (t >> 4) << 4;            // first of 16 rows this thread owns
    uint32_t dreg[RPT];
    const uint32_t* db = det + b * IMG_WORDS;
    #pragma unroll
    for (int k = 0; k < RPT; ++k) dreg[k] = db[(r0 + k) * WPR + w];

    // reduce this image's 256 block keys -> single argmax key
    unsigned long long kk = (t < 256) ? keys[b * 256 + t] : 0ull;
    #pragma unroll
    for (int s = 32; s > 0; s >>= 1) {
        unsigned long long o = __shfl_xor(kk, s);
        kk = o > kk ? o : kk;
    }
    if (lane == 0 && wvid < 4) redk[wvid] = kk;

    for (int i = t; i < 2 * WPR * STRIDE; i += 512) ((uint32_t*)hb)[i] = 0;
    if (t < 8) ep[t] = 0;
    __syncthreads();                     // the only full barrier (init)

    unsigned long long key = redk[0];
    key = redk[1] > key ? redk[1] : key;
    key = redk[2] > key ? redk[2] : key;
    key = redk[3] > key ? redk[3] : key;
    uint32_t pix = 0xFFFFFFFFu - (uint32_t)key;
    int sr = pix >> 9, sc = pix & 511;
    uint32_t curreg[RPT];
    #pragma unroll
    for (int k = 0; k < RPT; ++k)        // sparse seed, registers only
        curreg[k] = (sr == r0 + k && (sc >> 5) == w) ? (1u << (sc & 31)) : 0u;

    for (int it = 0; it < NPASS; ++it) {
        uint32_t* colv = &hb[it & 1][w * STRIDE];
        // ---- horizontal radius-10: DPP neighbors + u64 log-doubling --------
        uint32_t Dv[RPT];
        #pragma unroll
        for (int k = 0; k < RPT; ++k) {
            uint32_t bb = curreg[k];
            uint32_t aa = (uint32_t)__builtin_amdgcn_update_dpp(
                0, (int)bb, 0x111, 0xF, 0xF, true);   // word w-1 (0 at w==0)
            uint32_t cc = (uint32_t)__builtin_amdgcn_update_dpp(
                0, (int)bb, 0x101, 0xF, 0xF, true);   // word w+1 (0 at w==15)
            unsigned long long W = (unsigned long long)(aa >> 22)
                                 | ((unsigned long long)bb << 10)
                                 | ((unsigned long long)cc << 42);
            unsigned long long D = W | (W >> 1);      // [0,1]
            D |= D >> 2;                              // [0,3]
            D |= D >> 4;                              // [0,7]
            unsigned long long D7 = D;
            D |= D >> 8;                              // [0,15]
            D |= D7 >> 13;                            // | [13,20] = [0,20]
            Dv[k] = (uint32_t)D;
        }
        *(uint4*)&colv[r0 + GLO]      = make_uint4(Dv[0],  Dv[1],  Dv[2],  Dv[3]);
        *(uint4*)&colv[r0 + GLO + 4]  = make_uint4(Dv[4],  Dv[5],  Dv[6],  Dv[7]);
        *(uint4*)&colv[r0 + GLO + 8]  = make_uint4(Dv[8],  Dv[9],  Dv[10], Dv[11]);
        *(uint4*)&colv[r0 + GLO + 12] = make_uint4(Dv[12], Dv[13], Dv[14], Dv[15]);

        // publish own epoch (release: orders the 4 b128 stores first)
        if (lane == 0)
            __hip_atomic_store(&ep[wvid], (uint32_t)(it + 1),
                               __ATOMIC_RELEASE, __HIP_MEMORY_SCOPE_WORKGROUP);
        // wait only for vertical neighbors (acquire)
        uint32_t tgt = (uint32_t)(it + 1);
        if (wvid > 0) {
            int z = 0;
            while (__hip_atomic_load(&ep[wvid - 1], __ATOMIC_ACQUIRE,
                                     __HIP_MEMORY_SCOPE_WORKGROUP) < tgt
                   && z < (1 << 24)) { ++z; }
        }
        if (wvid < 7) {
            int z = 0;
            while (__hip_atomic_load(&ep[wvid + 1], __ATOMIC_ACQUIRE,
                                     __HIP_MEMORY_SCOPE_WORKGROUP) < tgt
                   && z < (1 << 24)) { ++z; }
        }

        // ---- vertical 21-row OR over 36-row window, log-doubling depth 5 ---
        uint32_t x[36];                  // x[j] = H-out of row (r0-10+j)
        {
            uint2 a0 = *(const uint2*)&colv[r0 + 2];      // rows r0-10,r0-9
            uint4 a1 = *(const uint4*)&colv[r0 + 4];      // rows r0-8..r0-5
            uint4 a2 = *(const uint4*)&colv[r0 + 8];      // rows r0-4..r0-1
            uint4 b0 = *(const uint4*)&colv[r0 + 28];     // rows r0+16..r0+19
            uint4 b1 = *(const uint4*)&colv[r0 + 32];     // rows r0+20..r0+23
            uint2 b2 = *(const uint2*)&colv[r0 + 36];     // rows r0+24,r0+25
            x[0] = a0.x;  x[1] = a0.y;
            x[2] = a1.x;  x[3] = a1.y;  x[4] = a1.z;  x[5] = a1.w;
            x[6] = a2.x;  x[7] = a2.y;  x[8] = a2.z;  x[9] = a2.w;
            #pragma unroll
            for (int k = 0; k < RPT; ++k) x[10 + k] = Dv[k];
            x[26] = b0.x; x[27] = b0.y; x[28] = b0.z; x[29] = b0.w;
            x[30] = b1.x; x[31] = b1.y; x[32] = b1.z; x[33] = b1.w;
            x[34] = b2.x; x[35] = b2.y;
        }
        uint32_t w1[35];
        #pragma unroll
        for (int i = 0; i < 35; ++i) w1[i] = x[i] | x[i + 1];     // [i,i+1]
        uint32_t w2[33];
        #pragma unroll
        for (int i = 0; i < 33; ++i) w2[i] = w1[i] | w1[i + 2];   // [i,i+3]
        uint32_t w4[29];
        #pragma unroll
        for (int i = 0; i < 29; ++i) w4[i] = w2[i] | w2[i + 4];   // [i,i+7]
        uint32_t w8[21];
        #pragma unroll
        for (int i = 0; i < 21; ++i) w8[i] = w4[i] | w4[i + 8];   // [i,i+15]
        #pragma unroll
        for (int k = 0; k < RPT; ++k)                             // [k,k+20]
            curreg[k] = dreg[k] & (w8[k] | w8[k + 5]);
    }
    #pragma unroll
    for (int k = 0; k < RPT; ++k)
        outmask[b * IMG_WORDS + (r0 + k) * WPR + w] = curreg[k];
}

// ---- Kernel 3: bits -> float, tiled 8x -------------------------------------
__global__ __launch_bounds__(256) void k_expand(const uint32_t* __restrict__ mask,
                                                float* __restrict__ out) {
    int t   = blockIdx.x * 256 + threadIdx.x;   // 4,194,304 threads, float4 each
    int img = t >> 16;                          // 65536 float4 per image
    int pix = (t & 65535) << 2;
    uint32_t wv = mask[(img & 7) * IMG_WORDS + (pix >> 5)];
    int sh = pix & 31;
    float4 o;
    o.x = (wv >> (sh + 0)) & 1 ? 1.0f : 0.0f;
    o.y = (wv >> (sh + 1)) & 1 ? 1.0f : 0.0f;
    o.z = (wv >> (sh + 2)) & 1 ? 1.0f : 0.0f;
    o.w = (wv >> (sh + 3)) & 1 ? 1.0f : 0.0f;
    ((float4*)out)[t] = o;
}

extern "C" void kernel_launch(void* const* d_in, const int* in_sizes, int n_in,
                              void* d_out, int out_size, void* d_ws, size_t ws_size,
                              hipStream_t stream) {
    const float* in = (const float*)d_in[0];
    float* out = (float*)d_out;
    unsigned long long* keys = (unsigned long long*)d_ws;          // 2048 x u64
    uint32_t* det = (uint32_t*)((char*)d_ws + 2048 * 8);
    uint32_t* fin = (uint32_t*)((char*)d_ws + 2048 * 8 + NB * IMG_WORDS * 4);

    k_det   <<<2048,  256, 0, stream>>>(in, det, keys);
    k_grow  <<<NB,    512, 0, stream>>>(det, keys, fin);
    k_expand<<<16384, 256, 0, stream>>>(fin, out);
}

// Round 11
// 94.952 us; speedup vs baseline: 1.2687x; 1.2687x over previous
//
#include <hip/hip_runtime.h>
#include <stdint.h>

#define HH 512
#define WW 512
#define NB 8
#define RAD 10
#define NPASS 51
#define WPR 16                 // u32 words per row
#define IMG_WORDS (HH*WPR)     // 8192 words per image
#define STRIDE 540             // words per LDS column: 12 low guard + 512 + 16 high guard
#define GLO 12                 // low guard rows (keeps b128 writes 16B-aligned)
#define RPT 16                 // rows per thread

typedef float floatx4 __attribute__((ext_vector_type(4)));

// ---- Kernel 1: det bits (x1>x0) + per-BLOCK argmax key (no atomics) --------
__global__ __launch_bounds__(256) void k_det(const float* __restrict__ in,
                                             uint32_t* __restrict__ det,
                                             unsigned long long* __restrict__ keys) {
    __shared__ unsigned long long red[4];
    int tid  = blockIdx.x * 256 + threadIdx.x;
    int lane = threadIdx.x & 63;
    int wv   = threadIdx.x >> 6;
    int wave = tid >> 6;
    long long base = (long long)wave * 256;     // 4 rounds x 64 pixels
    unsigned long long best = 0;
    const float2* in2 = (const float2*)in;
    #pragma unroll
    for (int j = 0; j < 4; ++j) {
        long long p = base + j * 64 + lane;
        float2 v = in2[p];
        // round(softmax_1(v)) == 1  <=>  v.y > v.x   (exact; no expf needed)
        float d = v.y - v.x;
        int pred = (d > 0.0f);
        unsigned long long bits = __ballot(pred);
        if (lane == 0) ((unsigned long long*)det)[wave * 4 + j] = bits;
        // argmax of softmax_1 == argmax of d (sigmoid strictly monotone).
        uint32_t du = __float_as_uint(d);
        uint32_t mono = (du & 0x80000000u) ? ~du : (du | 0x80000000u);
        uint32_t pix = (uint32_t)(p & (HH * WW - 1));
        unsigned long long key = ((unsigned long long)mono << 32)
                               | (unsigned long long)(0xFFFFFFFFu - pix);
        best = key > best ? key : best;
    }
    #pragma unroll
    for (int s = 32; s > 0; s >>= 1) {
        unsigned long long o = __shfl_xor(best, s);
        best = o > best ? o : best;
    }
    if (lane == 0) red[wv] = best;
    __syncthreads();
    if (threadIdx.x == 0) {
        unsigned long long b0 = red[0], b1 = red[1], b2 = red[2], b3 = red[3];
        b0 = b0 > b1 ? b0 : b1;
        b2 = b2 > b3 ? b2 : b3;
        keys[blockIdx.x] = b0 > b2 ? b0 : b2;   // plain store, no atomics
    }
}

// ---- Kernel 2: geodesic dilation, 512 thr x 16 rows, 1 barrier/iter --------
// Fixed 51 iterations (profiling showed no dispatch ever converges early;
// extra passes at a fixed point are idempotent -> bit-exact either way).
__global__ __launch_bounds__(512) void k_grow(const uint32_t* __restrict__ det,
                                              const unsigned long long* __restrict__ keys,
                                              uint32_t* __restrict__ outmask) {
    __shared__ __align__(16) uint32_t hb[2][WPR * STRIDE];  // 69 KB, col-major
    __shared__ unsigned long long redk[4];
    int b    = blockIdx.x;
    int t    = threadIdx.x;
    int lane = t & 63;
    int wvid = t >> 6;
    int w    = t & 15;                   // word-in-row == lane&15 (DPP row!)
    int r0   = (t >> 4) << 4;            // first of 16 rows this thread owns
    uint32_t dreg[RPT];
    const uint32_t* db = det + b * IMG_WORDS;
    #pragma unroll
    for (int k = 0; k < RPT; ++k) dreg[k] = db[(r0 + k) * WPR + w];

    // reduce this image's 256 block keys -> single argmax key
    unsigned long long kk = (t < 256) ? keys[b * 256 + t] : 0ull;
    #pragma unroll
    for (int s = 32; s > 0; s >>= 1) {
        unsigned long long o = __shfl_xor(kk, s);
        kk = o > kk ? o : kk;
    }
    if (lane == 0 && wvid < 4) redk[wvid] = kk;

    for (int i = t; i < 2 * WPR * STRIDE; i += 512) ((uint32_t*)hb)[i] = 0;
    __syncthreads();

    unsigned long long key = redk[0];
    key = redk[1] > key ? redk[1] : key;
    key = redk[2] > key ? redk[2] : key;
    key = redk[3] > key ? redk[3] : key;
    uint32_t pix = 0xFFFFFFFFu - (uint32_t)key;
    int sr = pix >> 9, sc = pix & 511;
    uint32_t curreg[RPT];
    #pragma unroll
    for (int k = 0; k < RPT; ++k)        // sparse seed, registers only
        curreg[k] = (sr == r0 + k && (sc >> 5) == w) ? (1u << (sc & 31)) : 0u;

    for (int it = 0; it < NPASS; ++it) {
        uint32_t* colv = &hb[it & 1][w * STRIDE];
        // ---- horizontal dilation radius 10: DPP neighbors + u64 log-doubling
        uint32_t Dv[RPT];
        #pragma unroll
        for (int k = 0; k < RPT; ++k) {
            uint32_t bb = curreg[k];
            uint32_t aa = (uint32_t)__builtin_amdgcn_update_dpp(
                0, (int)bb, 0x111, 0xF, 0xF, true);   // word w-1 (0 at w==0)
            uint32_t cc = (uint32_t)__builtin_amdgcn_update_dpp(
                0, (int)bb, 0x101, 0xF, 0xF, true);   // word w+1 (0 at w==15)
            unsigned long long W = (unsigned long long)(aa >> 22)
                                 | ((unsigned long long)bb << 10)
                                 | ((unsigned long long)cc << 42);
            unsigned long long D = W | (W >> 1);      // offsets [0,1]
            D |= D >> 2;                              // [0,3]
            D |= D >> 4;                              // [0,7]
            unsigned long long D7 = D;
            D |= D >> 8;                              // [0,15]
            D |= D7 >> 13;                            // | [13,20] = [0,20]
            Dv[k] = (uint32_t)D;
        }
        // store 16 contiguous rows of column w: 4x ds_write_b128
        *(uint4*)&colv[r0 + GLO]      = make_uint4(Dv[0],  Dv[1],  Dv[2],  Dv[3]);
        *(uint4*)&colv[r0 + GLO + 4]  = make_uint4(Dv[4],  Dv[5],  Dv[6],  Dv[7]);
        *(uint4*)&colv[r0 + GLO + 8]  = make_uint4(Dv[8],  Dv[9],  Dv[10], Dv[11]);
        *(uint4*)&colv[r0 + GLO + 12] = make_uint4(Dv[12], Dv[13], Dv[14], Dv[15]);
        __syncthreads();                 // the ONLY barrier per iteration

        // ---- vertical 21-row OR over 36-row window: prefix/suffix (minimal ops)
        uint32_t x[36];                  // x[j] = H-out of row (r0-10+j)
        {
            uint2 a0 = *(const uint2*)&colv[r0 + 2];      // rows r0-10,r0-9
            uint4 a1 = *(const uint4*)&colv[r0 + 4];      // rows r0-8..r0-5
            uint4 a2 = *(const uint4*)&colv[r0 + 8];      // rows r0-4..r0-1
            uint4 b0 = *(const uint4*)&colv[r0 + 28];     // rows r0+16..r0+19
            uint4 b1 = *(const uint4*)&colv[r0 + 32];     // rows r0+20..r0+23
            uint2 b2 = *(const uint2*)&colv[r0 + 36];     // rows r0+24,r0+25
            x[0] = a0.x;  x[1] = a0.y;
            x[2] = a1.x;  x[3] = a1.y;  x[4] = a1.z;  x[5] = a1.w;
            x[6] = a2.x;  x[7] = a2.y;  x[8] = a2.z;  x[9] = a2.w;
            #pragma unroll
            for (int k = 0; k < RPT; ++k) x[10 + k] = Dv[k];
            x[26] = b0.x; x[27] = b0.y; x[28] = b0.z; x[29] = b0.w;
            x[30] = b1.x; x[31] = b1.y; x[32] = b1.z; x[33] = b1.w;
            x[34] = b2.x; x[35] = b2.y;
        }
        uint32_t s[21];
        s[20] = x[20];
        #pragma unroll
        for (int i = 19; i >= 0; --i) s[i] = x[i] | s[i + 1];
        uint32_t p[36];
        p[21] = x[21];
        #pragma unroll
        for (int i = 22; i < 36; ++i) p[i] = x[i] | p[i - 1];
        curreg[0] = dreg[0] & s[0];
        #pragma unroll
        for (int k = 1; k < RPT; ++k)
            curreg[k] = dreg[k] & (s[k] | p[k + 20]);
    }
    #pragma unroll
    for (int k = 0; k < RPT; ++k)
        outmask[b * IMG_WORDS + (r0 + k) * WPR + w] = curreg[k];
}

// ---- Kernel 3: bits -> float, tiled 8x, nontemporal stores -----------------
__global__ __launch_bounds__(256) void k_expand(const uint32_t* __restrict__ mask,
                                                float* __restrict__ out) {
    int t   = blockIdx.x * 256 + threadIdx.x;   // 4,194,304 threads, float4 each
    int img = t >> 16;                          // 65536 float4 per image
    int pix = (t & 65535) << 2;
    uint32_t wv = mask[(img & 7) * IMG_WORDS + (pix >> 5)];
    int sh = pix & 31;
    floatx4 o;
    o.x = (wv >> (sh + 0)) & 1 ? 1.0f : 0.0f;
    o.y = (wv >> (sh + 1)) & 1 ? 1.0f : 0.0f;
    o.z = (wv >> (sh + 2)) & 1 ? 1.0f : 0.0f;
    o.w = (wv >> (sh + 3)) & 1 ? 1.0f : 0.0f;
    __builtin_nontemporal_store(o, (floatx4*)out + t);
}

extern "C" void kernel_launch(void* const* d_in, const int* in_sizes, int n_in,
                              void* d_out, int out_size, void* d_ws, size_t ws_size,
                              hipStream_t stream) {
    const float* in = (const float*)d_in[0];
    float* out = (float*)d_out;
    unsigned long long* keys = (unsigned long long*)d_ws;          // 2048 x u64
    uint32_t* det = (uint32_t*)((char*)d_ws + 2048 * 8);
    uint32_t* fin = (uint32_t*)((char*)d_ws + 2048 * 8 + NB * IMG_WORDS * 4);

    k_det   <<<2048,  256, 0, stream>>>(in, det, keys);
    k_grow  <<<NB,    512, 0, stream>>>(det, keys, fin);
    k_expand<<<16384, 256, 0, stream>>>(fin, out);
}